// Round 3
// baseline (118.410 us; speedup 1.0000x reference)
//
#include <hip/hip_runtime.h>
#include <math.h>

// DSS layer: y[h,l] = D[h]*u[h,l] + sum_{m<=l} K[h,m] * u[h,l-m]
// K[h,m] = Re( sum_n c_{h,n} * z_{h,n}^m ),  z = exp(step*lambda)
// c = (W/lambda) * conj(s) / (|s|^2 + EPS),  s = (1 - z^L)/(1 - z)
// (softmax argmax shift is a no-op: Re(lambda) = -0.5 < 0 => argmax at l=0)
//
// Single fused kernel: one block (256 thr = 4 waves) per channel.
// Threads 0..31 compute per-mode constants into LDS; wave w owns modes
// [8w, 8w+8) and scans the full sequence (lane t owns elements [32t,32t+32)).
// Cross-lane carry via in-wave Kogge-Stone with ratio z^32 (squared per round).
// Mode-partials summed through LDS atomics; epilogue adds D*u and stores.

static constexpr int kH = 1024;
static constexpr int kL = 2048;
static constexpr int kN = 32;
static constexpr int kChunk = 32;          // elements per lane
static constexpr int kWaves = 4;
static constexpr int kMpW = kN / kWaves;   // 8 modes per wave
static constexpr float kEps = 1e-7f;

__global__ __launch_bounds__(256, 4)
void dss_fused_kernel(const float* __restrict__ u,
                      const float* __restrict__ W,
                      const float* __restrict__ Lambda_ri,
                      const float* __restrict__ log_step,
                      const float* __restrict__ Dv,
                      float* __restrict__ y) {
    __shared__ float u_s[kL + (kL >> 5)];   // padded: stride-33 lane access, conflict-free
    __shared__ float y_s[kL + (kL >> 5)];
    __shared__ float p_s[kN][6];            // zr, zi, cr, ci, zCr, zCi

    const int h = blockIdx.x;
    const int tid = threadIdx.x;
    const int wave = tid >> 6;
    const int lane = tid & 63;

    const float* uh = u + (size_t)h * kL;
    for (int i = tid; i < kL; i += 256) {
        u_s[i + (i >> 5)] = uh[i];
        y_s[i + (i >> 5)] = 0.f;
    }

    // ---- Fused setup: one thread per mode ----
    if (tid < kN) {
        const int n = tid;
        const float step = expf(log_step[h]);
        const float lr = Lambda_ri[2 * n + 0];
        const float li = Lambda_ri[2 * n + 1];
        const float wr = W[(h * kN + n) * 2 + 0];
        const float wi = W[(h * kN + n) * 2 + 1];

        const float ar = step * lr;   // ~ -0.5*step < 0
        const float ai = step * li;

        const float ea = expf(ar);
        float sb, cb;
        sincosf(ai, &sb, &cb);

        // 1 - z, cancellation-safe: 1 - e^a cos b = -expm1(a)cos b + 2 sin^2(b/2)
        const float em = expm1f(ar);
        const float sh = sinf(0.5f * ai);
        const float dr = fmaf(-em, cb, 2.f * sh * sh);
        const float di = -ea * sb;

        // 1 - z^L (|z^L| <= e^-1, safe)
        const float eL = expf(ar * (float)kL);
        float sL, cL;
        sincosf(ai * (float)kL, &sL, &cL);
        const float nr = 1.f - eL * cL;
        const float ni = -eL * sL;

        // s = (1 - z^L)/(1 - z)
        const float dd = dr * dr + di * di;
        const float id = 1.f / dd;
        const float sr = (nr * dr + ni * di) * id;
        const float si = (ni * dr - nr * di) * id;

        // q = w / lambda
        const float ll = lr * lr + li * li;
        const float il = 1.f / ll;
        const float qr = (wr * lr + wi * li) * il;
        const float qi = (wi * lr - wr * li) * il;

        // c = q * conj(s) / (|s|^2 + EPS)
        const float ss = fmaf(sr, sr, fmaf(si, si, kEps));
        const float is = 1.f / ss;

        // zC = z^kChunk
        const float eC = expf(ar * (float)kChunk);
        float sC, cC;
        sincosf(ai * (float)kChunk, &sC, &cC);

        p_s[n][0] = ea * cb;
        p_s[n][1] = ea * sb;
        p_s[n][2] = (qr * sr + qi * si) * is;
        p_s[n][3] = (qi * sr - qr * si) * is;
        p_s[n][4] = eC * cC;
        p_s[n][5] = eC * sC;
    }
    __syncthreads();

    // ---- Load this wave's 8 mode constants (lane-uniform -> broadcast) ----
    const int m0 = wave * kMpW;
    float zr[kMpW], zi[kMpW], cr[kMpW], ci[kMpW];
#pragma unroll
    for (int n = 0; n < kMpW; ++n) {
        zr[n] = p_s[m0 + n][0];
        zi[n] = p_s[m0 + n][1];
        cr[n] = p_s[m0 + n][2];
        ci[n] = p_s[m0 + n][3];
    }

    // ---- Phase 1: zero-carry scan of own chunk -> end state per mode ----
    float er[kMpW], ei[kMpW];
#pragma unroll
    for (int n = 0; n < kMpW; ++n) { er[n] = 0.f; ei[n] = 0.f; }

    const int base = lane * kChunk;
    for (int k = 0; k < kChunk; ++k) {
        const int i = base + k;
        const float uv = u_s[i + (i >> 5)];
#pragma unroll
        for (int n = 0; n < kMpW; ++n) {
            const float tr = zi[n] * er[n];
            er[n] = fmaf(zr[n], er[n], fmaf(-zi[n], ei[n], uv));
            ei[n] = fmaf(zr[n], ei[n], tr);
        }
    }

    // ---- Phase 2: exclusive weighted scan across lanes (ratio z^32) ----
#pragma unroll
    for (int n = 0; n < kMpW; ++n) {
        const float vr = __shfl_up(er[n], 1);
        const float vi = __shfl_up(ei[n], 1);
        er[n] = (lane >= 1) ? vr : 0.f;
        ei[n] = (lane >= 1) ? vi : 0.f;
    }
    float pr[kMpW], pi[kMpW];
#pragma unroll
    for (int n = 0; n < kMpW; ++n) {
        pr[n] = p_s[m0 + n][4];
        pi[n] = p_s[m0 + n][5];
    }
#pragma unroll
    for (int d = 1; d < 64; d <<= 1) {
#pragma unroll
        for (int n = 0; n < kMpW; ++n) {
            float vr = __shfl_up(er[n], d);
            float vi = __shfl_up(ei[n], d);
            const bool ok = (lane >= d);
            vr = ok ? vr : 0.f;
            vi = ok ? vi : 0.f;
            er[n] = fmaf(pr[n], vr, fmaf(-pi[n], vi, er[n]));
            ei[n] = fmaf(pr[n], vi, fmaf(pi[n], vr, ei[n]));
        }
        if (d < 32) {
#pragma unroll
            for (int n = 0; n < kMpW; ++n) {
                const float t = fmaf(pr[n], pr[n], -pi[n] * pi[n]);
                pi[n] = 2.f * pr[n] * pi[n];
                pr[n] = t;
            }
        }
    }
    // er/ei = carry-in state entering chunk `lane` for this wave's modes.

    // ---- Phase 3: rescan with carry-in, accumulate mode-partials to LDS ----
    for (int k = 0; k < kChunk; ++k) {
        const int i = base + k;
        const float uv = u_s[i + (i >> 5)];
        float acc = 0.f;
#pragma unroll
        for (int n = 0; n < kMpW; ++n) {
            const float tr = zi[n] * er[n];
            er[n] = fmaf(zr[n], er[n], fmaf(-zi[n], ei[n], uv));
            ei[n] = fmaf(zr[n], ei[n], tr);
            acc = fmaf(cr[n], er[n], acc);
            acc = fmaf(-ci[n], ei[n], acc);
        }
        atomicAdd(&y_s[i + (i >> 5)], acc);   // ds_add_f32, conflict-free banks
    }
    __syncthreads();

    // ---- Epilogue: y = partials + D*u, coalesced ----
    const float Dh = Dv[h];
    float* yh = y + (size_t)h * kL;
    for (int i = tid; i < kL; i += 256) {
        yh[i] = fmaf(Dh, u_s[i + (i >> 5)], y_s[i + (i >> 5)]);
    }
}

extern "C" void kernel_launch(void* const* d_in, const int* in_sizes, int n_in,
                              void* d_out, int out_size, void* d_ws, size_t ws_size,
                              hipStream_t stream) {
    const float* u        = (const float*)d_in[0];  // (H, L)
    const float* W        = (const float*)d_in[1];  // (H, N, 2)
    const float* Lam      = (const float*)d_in[2];  // (N, 2)
    const float* log_step = (const float*)d_in[3];  // (H,)
    const float* Dv       = (const float*)d_in[4];  // (H,)
    float* y = (float*)d_out;                       // (H, L) fp32

    dss_fused_kernel<<<kH, 256, 0, stream>>>(u, W, Lam, log_step, Dv, y);
}

// Round 4
// 90.624 us; speedup vs baseline: 1.3066x; 1.3066x over previous
//
#include <hip/hip_runtime.h>
#include <math.h>

// DSS layer: y[h,l] = D[h]*u[h,l] + sum_{m<=l} K[h,m] * u[h,l-m]
// K[h,m] = Re( sum_n c_{h,n} * z_{h,n}^m ),  z = exp(step*lambda)
// c = (W/lambda) * conj(s) / (|s|^2 + EPS),  s = (1 - z^L)/(1 - z)
// (softmax argmax shift is a no-op: Re(lambda) = -0.5 < 0 => argmax at l=0)
//
// Two kernels:
//  1) setup: per (h,n) mode constants -> zc in ws (GLOBAL, so the scan kernel
//     can read them at wave-uniform addresses -> s_load -> SGPRs. R3 showed
//     LDS-resident constants un-scalarize and wreck the inner loop.)
//  2) scan: 1024 blocks x 256 thr (4 waves, 8 modes/wave). Lane t owns
//     elements [32t, 32t+32) IN REGISTERS. Kogge-Stone carry across lanes.
//     Per-wave private LDS partial buffers (no atomics), one syncthreads.

static constexpr int kH = 1024;
static constexpr int kL = 2048;
static constexpr int kN = 32;
static constexpr int kChunk = 32;          // elements per lane
static constexpr int kWaves = 4;
static constexpr int kMpW = kN / kWaves;   // 8 modes per wave
static constexpr float kEps = 1e-7f;
static constexpr int kYStride = kL + (kL >> 5) + 1;  // 2113: +1 shifts banks across buffers

// ws layout per (h,n): 8 floats: z_r, z_i, c_r, c_i, zC_r, zC_i, pad, pad
__global__ void dss_setup_kernel(const float* __restrict__ W,
                                 const float* __restrict__ Lambda_ri,
                                 const float* __restrict__ log_step,
                                 float* __restrict__ zc) {
    int idx = blockIdx.x * blockDim.x + threadIdx.x;  // h*kN + n
    if (idx >= kH * kN) return;
    int h = idx / kN;
    int n = idx % kN;

    float step = expf(log_step[h]);
    float lr = Lambda_ri[2 * n + 0];
    float li = Lambda_ri[2 * n + 1];
    float wr = W[(h * kN + n) * 2 + 0];
    float wi = W[(h * kN + n) * 2 + 1];

    float ar = step * lr;   // ~ -0.5*step < 0
    float ai = step * li;

    float ea = expf(ar);
    float sb, cb;
    sincosf(ai, &sb, &cb);

    // 1 - z, cancellation-safe: 1 - e^a cos b = -expm1(a)cos b + 2 sin^2(b/2)
    float em = expm1f(ar);
    float sh = sinf(0.5f * ai);
    float dr = fmaf(-em, cb, 2.f * sh * sh);
    float di = -ea * sb;

    // 1 - z^L (|z^L| <= e^-1, no cancellation)
    float eL = expf(ar * (float)kL);
    float sL, cL;
    sincosf(ai * (float)kL, &sL, &cL);
    float nr = 1.f - eL * cL;
    float ni = -eL * sL;

    // s = (1 - z^L)/(1 - z)
    float dd = dr * dr + di * di;
    float id = 1.f / dd;
    float sr = (nr * dr + ni * di) * id;
    float si = (ni * dr - nr * di) * id;

    // q = w / lambda
    float ll = lr * lr + li * li;
    float il = 1.f / ll;
    float qr = (wr * lr + wi * li) * il;
    float qi = (wi * lr - wr * li) * il;

    // c = q * conj(s) / (|s|^2 + EPS)
    float ss = fmaf(sr, sr, fmaf(si, si, kEps));
    float is = 1.f / ss;

    // zC = z^kChunk
    float eC = expf(ar * (float)kChunk);
    float sC, cC;
    sincosf(ai * (float)kChunk, &sC, &cC);

    float* o = zc + (size_t)idx * 8;
    o[0] = ea * cb;              o[1] = ea * sb;
    o[2] = (qr * sr + qi * si) * is;
    o[3] = (qi * sr - qr * si) * is;
    o[4] = eC * cC;              o[5] = eC * sC;
    o[6] = 0.f;                  o[7] = 0.f;
}

__global__ __launch_bounds__(256, 4)
void dss_scan_kernel(const float* __restrict__ u,
                     const float* __restrict__ zc,
                     const float* __restrict__ Dv,
                     float* __restrict__ y) {
    __shared__ float y_s[kWaves][kYStride];   // 33.8 KB

    const int h = blockIdx.x;
    const int tid = threadIdx.x;
    const int wave = tid >> 6;
    const int lane = tid & 63;

    // ---- u: this lane's 32 elements -> registers (8x float4) ----
    const float4* uh4 = (const float4*)(u + (size_t)h * kL) + lane * 8;
    float uu[kChunk];
#pragma unroll
    for (int k = 0; k < 8; ++k) {
        const float4 v = uh4[k];
        uu[4 * k + 0] = v.x; uu[4 * k + 1] = v.y;
        uu[4 * k + 2] = v.z; uu[4 * k + 3] = v.w;
    }

    // ---- mode constants: wave-uniform global addresses -> s_load -> SGPR ----
    const int m0 = __builtin_amdgcn_readfirstlane((tid >> 6) * kMpW);
    const float* zch = zc + ((size_t)h * kN + m0) * 8;
    float zr[kMpW], zi[kMpW], cr[kMpW], ci[kMpW];
#pragma unroll
    for (int n = 0; n < kMpW; ++n) {
        zr[n] = zch[n * 8 + 0];
        zi[n] = zch[n * 8 + 1];
        cr[n] = zch[n * 8 + 2];
        ci[n] = zch[n * 8 + 3];
    }

    // ---- Phase 1: zero-carry scan of own chunk -> end state per mode ----
    float er[kMpW], ei[kMpW];
#pragma unroll
    for (int n = 0; n < kMpW; ++n) { er[n] = 0.f; ei[n] = 0.f; }

#pragma unroll
    for (int k = 0; k < kChunk; ++k) {
        const float uv = uu[k];
#pragma unroll
        for (int n = 0; n < kMpW; ++n) {
            const float tr = zi[n] * er[n];
            er[n] = fmaf(zr[n], er[n], fmaf(-zi[n], ei[n], uv));
            ei[n] = fmaf(zr[n], ei[n], tr);
        }
    }

    // ---- Phase 2: exclusive weighted scan across 64 lanes (ratio z^32) ----
#pragma unroll
    for (int n = 0; n < kMpW; ++n) {
        const float vr = __shfl_up(er[n], 1);
        const float vi = __shfl_up(ei[n], 1);
        er[n] = (lane >= 1) ? vr : 0.f;
        ei[n] = (lane >= 1) ? vi : 0.f;
    }
    float pr[kMpW], pi[kMpW];
#pragma unroll
    for (int n = 0; n < kMpW; ++n) {
        pr[n] = zch[n * 8 + 4];
        pi[n] = zch[n * 8 + 5];
    }
#pragma unroll
    for (int d = 1; d < 64; d <<= 1) {
#pragma unroll
        for (int n = 0; n < kMpW; ++n) {
            float vr = __shfl_up(er[n], d);
            float vi = __shfl_up(ei[n], d);
            const bool ok = (lane >= d);
            vr = ok ? vr : 0.f;
            vi = ok ? vi : 0.f;
            er[n] = fmaf(pr[n], vr, fmaf(-pi[n], vi, er[n]));
            ei[n] = fmaf(pr[n], vi, fmaf(pi[n], vr, ei[n]));
        }
        if (d < 32) {
#pragma unroll
            for (int n = 0; n < kMpW; ++n) {
                const float t = fmaf(pr[n], pr[n], -pi[n] * pi[n]);
                pi[n] = 2.f * pr[n] * pi[n];
                pr[n] = t;
            }
        }
    }
    // er/ei = carry-in state entering chunk `lane` for this wave's modes.

    // ---- Phase 3: rescan with carry-in, private partials to LDS ----
    const float Dh = Dv[h];
    float* ys = &y_s[wave][0] + lane * 33;   // lane-private 33-float stripe
#pragma unroll
    for (int k = 0; k < kChunk; ++k) {
        const float uv = uu[k];
        float acc = (wave == 0) ? Dh * uv : 0.f;
#pragma unroll
        for (int n = 0; n < kMpW; ++n) {
            const float tr = zi[n] * er[n];
            er[n] = fmaf(zr[n], er[n], fmaf(-zi[n], ei[n], uv));
            ei[n] = fmaf(zr[n], ei[n], tr);
            acc = fmaf(cr[n], er[n], acc);
            acc = fmaf(-ci[n], ei[n], acc);
        }
        ys[k] = acc;   // bank = (lane+k) % 32 -> 2 lanes/bank, free
    }
    __syncthreads();

    // ---- Epilogue: sum 4 wave-partials, coalesced store ----
    float* yh = y + (size_t)h * kL;
    for (int i = tid; i < kL; i += 256) {
        const int idx = i + (i >> 5);
        yh[i] = (y_s[0][idx] + y_s[1][idx]) + (y_s[2][idx] + y_s[3][idx]);
    }
}

extern "C" void kernel_launch(void* const* d_in, const int* in_sizes, int n_in,
                              void* d_out, int out_size, void* d_ws, size_t ws_size,
                              hipStream_t stream) {
    const float* u        = (const float*)d_in[0];  // (H, L)
    const float* W        = (const float*)d_in[1];  // (H, N, 2)
    const float* Lam      = (const float*)d_in[2];  // (N, 2)
    const float* log_step = (const float*)d_in[3];  // (H,)
    const float* Dv       = (const float*)d_in[4];  // (H,)
    float* y  = (float*)d_out;                      // (H, L) fp32
    float* zc = (float*)d_ws;                       // H*N*8 floats = 1 MB

    dss_setup_kernel<<<(kH * kN + 255) / 256, 256, 0, stream>>>(W, Lam, log_step, zc);
    dss_scan_kernel<<<kH, 256, 0, stream>>>(u, zc, Dv, y);
}

// Round 5
// 88.286 us; speedup vs baseline: 1.3412x; 1.0265x over previous
//
#include <hip/hip_runtime.h>
#include <math.h>

// DSS layer: y[h,l] = D[h]*u[h,l] + sum_{m<=l} K[h,m] * u[h,l-m]
// K[h,m] = Re( sum_n c_{h,n} * z_{h,n}^m ),  z = exp(step*lambda)
// c = (W/lambda) * conj(s) / (|s|^2 + EPS),  s = (1 - z^L)/(1 - z)
// (softmax argmax shift is a no-op: Re(lambda) = -0.5 < 0 => argmax at l=0)
//
// R5: same decomposition as R4 (1024 blocks x 4 waves, 8 modes/wave,
// lane t owns elements [32t,32t+32), Kogge-Stone carry, SGPR constants
// from global zc), but with ROLLED k-loops: R1-R4 fully unrolled the
// 32x8 FMA loops into 20-80 KB straight-line code that overflows the
// 32 KB L1I -> front-end streams from L2 -> all-wave stall (~75% idle,
// invariant to occupancy). u is consumed as just-in-time float4 with
// 1-deep prefetch instead of a 32-register array (rule #20 safe).

static constexpr int kH = 1024;
static constexpr int kL = 2048;
static constexpr int kN = 32;
static constexpr int kWaves = 4;
static constexpr int kMpW = kN / kWaves;   // 8 modes per wave
static constexpr float kEps = 1e-7f;
static constexpr int kYStride = kL + (kL >> 5) + 1;  // 2113

// ws layout per (h,n): 8 floats: z_r, z_i, c_r, c_i, zC_r, zC_i, pad, pad
__global__ void dss_setup_kernel(const float* __restrict__ W,
                                 const float* __restrict__ Lambda_ri,
                                 const float* __restrict__ log_step,
                                 float* __restrict__ zc) {
    int idx = blockIdx.x * blockDim.x + threadIdx.x;  // h*kN + n
    if (idx >= kH * kN) return;
    int h = idx / kN;
    int n = idx % kN;

    float step = expf(log_step[h]);
    float lr = Lambda_ri[2 * n + 0];
    float li = Lambda_ri[2 * n + 1];
    float wr = W[(h * kN + n) * 2 + 0];
    float wi = W[(h * kN + n) * 2 + 1];

    float ar = step * lr;   // ~ -0.5*step < 0
    float ai = step * li;

    float ea = expf(ar);
    float sb, cb;
    sincosf(ai, &sb, &cb);

    // 1 - z, cancellation-safe: 1 - e^a cos b = -expm1(a)cos b + 2 sin^2(b/2)
    float em = expm1f(ar);
    float sh = sinf(0.5f * ai);
    float dr = fmaf(-em, cb, 2.f * sh * sh);
    float di = -ea * sb;

    // 1 - z^L (|z^L| <= e^-1, no cancellation)
    float eL = expf(ar * (float)kL);
    float sL, cL;
    sincosf(ai * (float)kL, &sL, &cL);
    float nr = 1.f - eL * cL;
    float ni = -eL * sL;

    // s = (1 - z^L)/(1 - z)
    float dd = dr * dr + di * di;
    float id = 1.f / dd;
    float sr = (nr * dr + ni * di) * id;
    float si = (ni * dr - nr * di) * id;

    // q = w / lambda
    float ll = lr * lr + li * li;
    float il = 1.f / ll;
    float qr = (wr * lr + wi * li) * il;
    float qi = (wi * lr - wr * li) * il;

    // c = q * conj(s) / (|s|^2 + EPS)
    float ss = fmaf(sr, sr, fmaf(si, si, kEps));
    float is = 1.f / ss;

    // zC = z^32
    float eC = expf(ar * 32.f);
    float sC, cC;
    sincosf(ai * 32.f, &sC, &cC);

    float* o = zc + (size_t)idx * 8;
    o[0] = ea * cb;              o[1] = ea * sb;
    o[2] = (qr * sr + qi * si) * is;
    o[3] = (qi * sr - qr * si) * is;
    o[4] = eC * cC;              o[5] = eC * sC;
    o[6] = 0.f;                  o[7] = 0.f;
}

__global__ __launch_bounds__(256, 4)
void dss_scan_kernel(const float* __restrict__ u,
                     const float* __restrict__ zc,
                     const float* __restrict__ Dv,
                     float* __restrict__ y) {
    __shared__ float y_s[kWaves][kYStride];   // 33.8 KB (grid caps at 4 blk/CU anyway)

    const int h = blockIdx.x;
    const int tid = threadIdx.x;
    const int wave = tid >> 6;
    const int lane = tid & 63;

    const float4* uh4 = (const float4*)(u + (size_t)h * kL) + lane * 8;

    // ---- mode constants: wave-uniform global addresses -> s_load -> SGPR ----
    const int m0 = __builtin_amdgcn_readfirstlane((tid >> 6) * kMpW);
    const float* zch = zc + ((size_t)h * kN + m0) * 8;
    float zr[kMpW], zi[kMpW], cr[kMpW], ci[kMpW];
#pragma unroll
    for (int n = 0; n < kMpW; ++n) {
        zr[n] = zch[n * 8 + 0];
        zi[n] = zch[n * 8 + 1];
        cr[n] = zch[n * 8 + 2];
        ci[n] = zch[n * 8 + 3];
    }

    // ---- Phase 1: zero-carry scan of own chunk (rolled, JIT float4 u) ----
    float er[kMpW], ei[kMpW];
#pragma unroll
    for (int n = 0; n < kMpW; ++n) { er[n] = 0.f; ei[n] = 0.f; }

    float4 v = uh4[0];
#pragma unroll 1
    for (int kk = 0; kk < 8; ++kk) {
        const float4 vn = uh4[(kk + 1) & 7];   // 1-deep prefetch (wrap on last)
        const float uvs[4] = {v.x, v.y, v.z, v.w};
#pragma unroll
        for (int j = 0; j < 4; ++j) {
            const float uv = uvs[j];
#pragma unroll
            for (int n = 0; n < kMpW; ++n) {
                const float tr = zi[n] * er[n];
                er[n] = fmaf(zr[n], er[n], fmaf(-zi[n], ei[n], uv));
                ei[n] = fmaf(zr[n], ei[n], tr);
            }
        }
        v = vn;
    }

    // ---- Phase 2: exclusive weighted scan across 64 lanes (ratio z^32) ----
#pragma unroll
    for (int n = 0; n < kMpW; ++n) {
        const float vr = __shfl_up(er[n], 1);
        const float vi = __shfl_up(ei[n], 1);
        er[n] = (lane >= 1) ? vr : 0.f;
        ei[n] = (lane >= 1) ? vi : 0.f;
    }
    float pr[kMpW], pi[kMpW];
#pragma unroll
    for (int n = 0; n < kMpW; ++n) {
        pr[n] = zch[n * 8 + 4];
        pi[n] = zch[n * 8 + 5];
    }
#pragma unroll 1
    for (int d = 1; d < 64; d <<= 1) {
#pragma unroll
        for (int n = 0; n < kMpW; ++n) {
            float vr = __shfl_up(er[n], d);
            float vi = __shfl_up(ei[n], d);
            const bool ok = (lane >= d);
            vr = ok ? vr : 0.f;
            vi = ok ? vi : 0.f;
            er[n] = fmaf(pr[n], vr, fmaf(-pi[n], vi, er[n]));
            ei[n] = fmaf(pr[n], vi, fmaf(pi[n], vr, ei[n]));
        }
#pragma unroll
        for (int n = 0; n < kMpW; ++n) {   // always square (|zC|<=1, safe)
            const float t = fmaf(pr[n], pr[n], -pi[n] * pi[n]);
            pi[n] = 2.f * pr[n] * pi[n];
            pr[n] = t;
        }
    }
    // er/ei = carry-in state entering chunk `lane` for this wave's modes.

    // ---- Phase 3: rescan with carry-in (rolled), private partials to LDS ----
    const float Dh = Dv[h];
    float* ys = &y_s[wave][0] + lane * 33;   // lane-private stripe, 2 lanes/bank
    float4 w4 = uh4[0];
#pragma unroll 1
    for (int kk = 0; kk < 8; ++kk) {
        const float4 wn = uh4[(kk + 1) & 7];
        const float uvs[4] = {w4.x, w4.y, w4.z, w4.w};
#pragma unroll
        for (int j = 0; j < 4; ++j) {
            const float uv = uvs[j];
            float acc = (wave == 0) ? Dh * uv : 0.f;
#pragma unroll
            for (int n = 0; n < kMpW; ++n) {
                const float tr = zi[n] * er[n];
                er[n] = fmaf(zr[n], er[n], fmaf(-zi[n], ei[n], uv));
                ei[n] = fmaf(zr[n], ei[n], tr);
                acc = fmaf(cr[n], er[n], acc);
                acc = fmaf(-ci[n], ei[n], acc);
            }
            ys[kk * 4 + j] = acc;
        }
        w4 = wn;
    }
    __syncthreads();

    // ---- Epilogue: sum 4 wave-partials, coalesced store ----
    float* yh = y + (size_t)h * kL;
    for (int i = tid; i < kL; i += 256) {
        const int idx = i + (i >> 5);
        yh[i] = (y_s[0][idx] + y_s[1][idx]) + (y_s[2][idx] + y_s[3][idx]);
    }
}

extern "C" void kernel_launch(void* const* d_in, const int* in_sizes, int n_in,
                              void* d_out, int out_size, void* d_ws, size_t ws_size,
                              hipStream_t stream) {
    const float* u        = (const float*)d_in[0];  // (H, L)
    const float* W        = (const float*)d_in[1];  // (H, N, 2)
    const float* Lam      = (const float*)d_in[2];  // (N, 2)
    const float* log_step = (const float*)d_in[3];  // (H,)
    const float* Dv       = (const float*)d_in[4];  // (H,)
    float* y  = (float*)d_out;                      // (H, L) fp32
    float* zc = (float*)d_ws;                       // H*N*8 floats = 1 MB

    dss_setup_kernel<<<(kH * kN + 255) / 256, 256, 0, stream>>>(W, Lam, log_step, zc);
    dss_scan_kernel<<<kH, 256, 0, stream>>>(u, zc, Dv, y);
}

// Round 7
// 87.304 us; speedup vs baseline: 1.3563x; 1.0112x over previous
//
#include <hip/hip_runtime.h>
#include <math.h>

// DSS layer: y[h,l] = D[h]*u[h,l] + sum_{m<=l} K[h,m] * u[h,l-m]
// K[h,m] = Re( sum_n c_{h,n} * z_{h,n}^m ),  z = exp(step*lambda)
// c = (W/lambda) * conj(s) / (|s|^2 + EPS),  s = (1 - z^L)/(1 - z)
// (softmax argmax shift is a no-op: Re(lambda) = -0.5 < 0 => argmax at l=0)
//
// R7 = R6 resubmitted (R6 hit a GPU-acquisition timeout; no data).
// Same decomposition as R4/R5 (1024 blocks x 4 waves, 8 modes/wave,
// lane t owns elements [32t,32t+32), Kogge-Stone carry, SGPR constants),
// but phases 1/3 use PACKED FP32 (v_pk_fma_f32, VOP3P) via inline asm:
//   X=(er,ei):  t  = pk_fma(ZP<-zi,zi>, swap(X), (uv,0))   [op_sel swap]
//               X' = pk_fma(ZP<zr,zr>,  X,       t)
//   acc:        P += (cr*er', -ci*ei')                      [neg_hi]
// 2 instrs/mode/elem for the recurrence (vs 4 scalar), 1 for accumulation
// (vs 2). Constants live in SGPR pairs (one SGPR source per VOP3P: legal).

static constexpr int kH = 1024;
static constexpr int kL = 2048;
static constexpr int kN = 32;
static constexpr int kWaves = 4;
static constexpr int kMpW = kN / kWaves;   // 8 modes per wave
static constexpr float kEps = 1e-7f;
static constexpr int kYStride = kL + (kL >> 5) + 1;  // 2113

using v2f = __attribute__((ext_vector_type(2))) float;

// t = ( -zi*ei + uv ,  zi*er + 0 )   with ZP=(zr,zi), X=(er,ei), U=(uv,0)
#define PK_CROSS(t, ZP, X, U)                                              \
    asm("v_pk_fma_f32 %0, %1, %2, %3 op_sel:[1,1,0] op_sel_hi:[1,0,1] "    \
        "neg_lo:[1,0,0]"                                                   \
        : "=v"(t) : "s"(ZP), "v"(X), "v"(U))

// X' = ( zr*er + t.lo , zr*ei + t.hi )  (S0 lo-broadcast)
#define PK_AXPY(Xo, ZP, Xi, T)                                             \
    asm("v_pk_fma_f32 %0, %1, %2, %3 op_sel_hi:[0,1,1]"                    \
        : "=v"(Xo) : "s"(ZP), "v"(Xi), "v"(T))

// P += ( cr*er , -ci*ei )   with CP=(cr,ci)
#define PK_ACC(P, CP, X)                                                   \
    asm("v_pk_fma_f32 %0, %1, %2, %0 neg_hi:[1,0,0]"                       \
        : "+v"(P) : "s"(CP), "v"(X))

// ws layout per (h,n): 8 floats: z_r, z_i, c_r, c_i, zC_r, zC_i, pad, pad
__global__ void dss_setup_kernel(const float* __restrict__ W,
                                 const float* __restrict__ Lambda_ri,
                                 const float* __restrict__ log_step,
                                 float* __restrict__ zc) {
    int idx = blockIdx.x * blockDim.x + threadIdx.x;  // h*kN + n
    if (idx >= kH * kN) return;
    int h = idx / kN;
    int n = idx % kN;

    float step = expf(log_step[h]);
    float lr = Lambda_ri[2 * n + 0];
    float li = Lambda_ri[2 * n + 1];
    float wr = W[(h * kN + n) * 2 + 0];
    float wi = W[(h * kN + n) * 2 + 1];

    float ar = step * lr;   // ~ -0.5*step < 0
    float ai = step * li;

    float ea = expf(ar);
    float sb, cb;
    sincosf(ai, &sb, &cb);

    // 1 - z, cancellation-safe: 1 - e^a cos b = -expm1(a)cos b + 2 sin^2(b/2)
    float em = expm1f(ar);
    float sh = sinf(0.5f * ai);
    float dr = fmaf(-em, cb, 2.f * sh * sh);
    float di = -ea * sb;

    // 1 - z^L (|z^L| <= e^-1, no cancellation)
    float eL = expf(ar * (float)kL);
    float sL, cL;
    sincosf(ai * (float)kL, &sL, &cL);
    float nr = 1.f - eL * cL;
    float ni = -eL * sL;

    // s = (1 - z^L)/(1 - z)
    float dd = dr * dr + di * di;
    float id = 1.f / dd;
    float sr = (nr * dr + ni * di) * id;
    float si = (ni * dr - nr * di) * id;

    // q = w / lambda
    float ll = lr * lr + li * li;
    float il = 1.f / ll;
    float qr = (wr * lr + wi * li) * il;
    float qi = (wi * lr - wr * li) * il;

    // c = q * conj(s) / (|s|^2 + EPS)
    float ss = fmaf(sr, sr, fmaf(si, si, kEps));
    float is = 1.f / ss;

    // zC = z^32
    float eC = expf(ar * 32.f);
    float sC, cC;
    sincosf(ai * 32.f, &sC, &cC);

    float* o = zc + (size_t)idx * 8;
    o[0] = ea * cb;              o[1] = ea * sb;
    o[2] = (qr * sr + qi * si) * is;
    o[3] = (qi * sr - qr * si) * is;
    o[4] = eC * cC;              o[5] = eC * sC;
    o[6] = 0.f;                  o[7] = 0.f;
}

__global__ __launch_bounds__(256, 4)
void dss_scan_kernel(const float* __restrict__ u,
                     const float* __restrict__ zc,
                     const float* __restrict__ Dv,
                     float* __restrict__ y) {
    __shared__ float y_s[kWaves][kYStride];   // 33.8 KB

    const int h = blockIdx.x;
    const int tid = threadIdx.x;
    const int wave = tid >> 6;
    const int lane = tid & 63;

    const float4* uh4 = (const float4*)(u + (size_t)h * kL) + lane * 8;

    // ---- mode constants: wave-uniform global addresses -> s_load pairs ----
    const int m0 = __builtin_amdgcn_readfirstlane((tid >> 6) * kMpW);
    const float* zch = zc + ((size_t)h * kN + m0) * 8;
    v2f zp[kMpW], cp[kMpW];
#pragma unroll
    for (int n = 0; n < kMpW; ++n) {
        zp[n] = *(const v2f*)(zch + n * 8 + 0);   // (zr, zi)
        cp[n] = *(const v2f*)(zch + n * 8 + 2);   // (cr, ci)
    }

    // ---- Phase 1: zero-carry scan of own chunk (packed, rolled) ----
    v2f X[kMpW];
#pragma unroll
    for (int n = 0; n < kMpW; ++n) X[n] = (v2f){0.f, 0.f};

    v2f U;
    U.y = 0.f;

    float4 v = uh4[0];
#pragma unroll 1
    for (int kk = 0; kk < 8; ++kk) {
        const float4 vn = uh4[(kk + 1) & 7];   // 1-deep prefetch (wrap on last)
        const float uvs[4] = {v.x, v.y, v.z, v.w};
#pragma unroll
        for (int j = 0; j < 4; ++j) {
            U.x = uvs[j];
#pragma unroll
            for (int n = 0; n < kMpW; ++n) {
                v2f t;
                PK_CROSS(t, zp[n], X[n], U);
                PK_AXPY(X[n], zp[n], X[n], t);
            }
        }
        v = vn;
    }

    // ---- Phase 2: exclusive weighted scan across 64 lanes (scalar) ----
#pragma unroll
    for (int n = 0; n < kMpW; ++n) {
        const float vr = __shfl_up(X[n].x, 1);
        const float vi = __shfl_up(X[n].y, 1);
        X[n].x = (lane >= 1) ? vr : 0.f;
        X[n].y = (lane >= 1) ? vi : 0.f;
    }
    float pr[kMpW], pi[kMpW];
#pragma unroll
    for (int n = 0; n < kMpW; ++n) {
        pr[n] = zch[n * 8 + 4];
        pi[n] = zch[n * 8 + 5];
    }
#pragma unroll 1
    for (int d = 1; d < 64; d <<= 1) {
#pragma unroll
        for (int n = 0; n < kMpW; ++n) {
            float vr = __shfl_up(X[n].x, d);
            float vi = __shfl_up(X[n].y, d);
            const bool ok = (lane >= d);
            vr = ok ? vr : 0.f;
            vi = ok ? vi : 0.f;
            X[n].x = fmaf(pr[n], vr, fmaf(-pi[n], vi, X[n].x));
            X[n].y = fmaf(pr[n], vi, fmaf(pi[n], vr, X[n].y));
        }
#pragma unroll
        for (int n = 0; n < kMpW; ++n) {   // square ratio (|zC|<=1, safe)
            const float t = fmaf(pr[n], pr[n], -pi[n] * pi[n]);
            pi[n] = 2.f * pr[n] * pi[n];
            pr[n] = t;
        }
    }
    // X[n] = carry-in state entering chunk `lane` for this wave's modes.

    // ---- Phase 3: rescan with carry-in (packed), partials to LDS ----
    const float dsel = (wave == 0) ? Dv[h] : 0.f;   // wave-uniform
    float* ys = &y_s[wave][0] + lane * 33;          // 2 lanes/bank: free
    float4 w4 = uh4[0];
#pragma unroll 1
    for (int kk = 0; kk < 8; ++kk) {
        const float4 wn = uh4[(kk + 1) & 7];
        const float uvs[4] = {w4.x, w4.y, w4.z, w4.w};
#pragma unroll
        for (int j = 0; j < 4; ++j) {
            const float uv = uvs[j];
            U.x = uv;
            v2f P0 = (v2f){dsel * uv, 0.f};
            v2f P1 = (v2f){0.f, 0.f};
#pragma unroll
            for (int n = 0; n < kMpW; ++n) {
                v2f t;
                PK_CROSS(t, zp[n], X[n], U);
                PK_AXPY(X[n], zp[n], X[n], t);
                if (n & 1) { PK_ACC(P1, cp[n], X[n]); }
                else       { PK_ACC(P0, cp[n], X[n]); }
            }
            const v2f P = P0 + P1;      // v_pk_add_f32
            ys[kk * 4 + j] = P.x + P.y;
        }
        w4 = wn;
    }
    __syncthreads();

    // ---- Epilogue: sum 4 wave-partials, coalesced store ----
    float* yh = y + (size_t)h * kL;
    for (int i = tid; i < kL; i += 256) {
        const int idx = i + (i >> 5);
        yh[i] = (y_s[0][idx] + y_s[1][idx]) + (y_s[2][idx] + y_s[3][idx]);
    }
}

extern "C" void kernel_launch(void* const* d_in, const int* in_sizes, int n_in,
                              void* d_out, int out_size, void* d_ws, size_t ws_size,
                              hipStream_t stream) {
    const float* u        = (const float*)d_in[0];  // (H, L)
    const float* W        = (const float*)d_in[1];  // (H, N, 2)
    const float* Lam      = (const float*)d_in[2];  // (N, 2)
    const float* log_step = (const float*)d_in[3];  // (H,)
    const float* Dv       = (const float*)d_in[4];  // (H,)
    float* y  = (float*)d_out;                      // (H, L) fp32
    float* zc = (float*)d_ws;                       // H*N*8 floats = 1 MB

    dss_setup_kernel<<<(kH * kN + 255) / 256, 256, 0, stream>>>(W, Lam, log_step, zc);
    dss_scan_kernel<<<kH, 256, 0, stream>>>(u, zc, Dv, y);
}